// Round 1
// baseline (279.716 us; speedup 1.0000x reference)
//
#include <hip/hip_runtime.h>

// VelVector: per point n (N=500000), K=32 neighbors, D=3.
//   nd[k] = normalize(neighbors[n,k]-pos[n]); w[k] = MLP(nd[k]) (3->5->5->1);
//   out[n] = normalize(sum_k nd[k]*w[k])
//
// Mapping: one lane per (point, neighbor). K=32 == half-wave, so a wave64
// handles 2 points. Lane l reads neighbors[n, l, 0..2]: 3 dword loads at
// 12 B lane stride over a contiguous 384 B/point region -> every cache line
// fully consumed. MLP weights are wave-uniform -> scalar loads (free).
// 32-lane butterfly shfl_xor reduces the weighted sum.

#define K 32

__global__ __launch_bounds__(256) void velvec_kernel(
    const float* __restrict__ pos,   // [N,3]
    const float* __restrict__ nbr,   // [N,K,3]
    const float* __restrict__ W1,    // [5,3]
    const float* __restrict__ b1,    // [5]
    const float* __restrict__ W2,    // [5,5]
    const float* __restrict__ b2,    // [5]
    const float* __restrict__ W3,    // [1,5]
    const float* __restrict__ b3,    // [1]
    float* __restrict__ out,         // [N,3]
    int N)
{
    const int lane  = threadIdx.x & (K - 1);                     // neighbor idx
    const int point = (int)((blockIdx.x * blockDim.x + threadIdx.x) >> 5);
    if (point >= N) return;

    // ---- weights: uniform addresses -> compiler emits s_load (per-wave) ----
    float w1[5][3], bb1[5], w2[5][5], bb2[5], w3[5];
#pragma unroll
    for (int h = 0; h < 5; ++h) {
        bb1[h] = b1[h];
        bb2[h] = b2[h];
        w3[h]  = W3[h];
#pragma unroll
        for (int d = 0; d < 3; ++d) w1[h][d] = W1[h * 3 + d];
#pragma unroll
        for (int g = 0; g < 5; ++g) w2[h][g] = W2[h * 5 + g];
    }
    const float bb3 = b3[0];

    // ---- position (broadcast within half-wave: same address) ----
    const float px = pos[point * 3 + 0];
    const float py = pos[point * 3 + 1];
    const float pz = pos[point * 3 + 2];

    // ---- neighbor diff + normalize ----
    const float* nb = nbr + (size_t)point * (K * 3) + lane * 3;
    float dx = nb[0] - px;
    float dy = nb[1] - py;
    float dz = nb[2] - pz;
    float n2 = dx * dx + dy * dy + dz * dz;
    // semantics: v / max(sqrt(n2), 1e-12). If norm<=1e-12 => inv = 1e12.
    float inv = (n2 > 1e-24f) ? __builtin_amdgcn_rsqf(n2) : 1e12f;
    dx *= inv; dy *= inv; dz *= inv;

    // ---- tiny MLP: 3 -> 5 (relu) -> 5 (relu) -> 1 ----
    float h1[5];
#pragma unroll
    for (int h = 0; h < 5; ++h) {
        float a = bb1[h];
        a = fmaf(w1[h][0], dx, a);
        a = fmaf(w1[h][1], dy, a);
        a = fmaf(w1[h][2], dz, a);
        h1[h] = fmaxf(a, 0.0f);
    }
    float h2[5];
#pragma unroll
    for (int g = 0; g < 5; ++g) {
        float a = bb2[g];
#pragma unroll
        for (int h = 0; h < 5; ++h) a = fmaf(w2[g][h], h1[h], a);
        h2[g] = fmaxf(a, 0.0f);
    }
    float w = bb3;
#pragma unroll
    for (int h = 0; h < 5; ++h) w = fmaf(w3[h], h2[h], w);

    // ---- weighted sum over the 32 neighbors (butterfly within half-wave) ----
    float vx = dx * w, vy = dy * w, vz = dz * w;
#pragma unroll
    for (int m = 16; m > 0; m >>= 1) {
        vx += __shfl_xor(vx, m, K);
        vy += __shfl_xor(vy, m, K);
        vz += __shfl_xor(vz, m, K);
    }

    // ---- final normalize + store (lanes 0..2 write x,y,z) ----
    float vn2  = vx * vx + vy * vy + vz * vz;
    float vinv = (vn2 > 1e-24f) ? __builtin_amdgcn_rsqf(vn2) : 1e12f;
    if (lane < 3) {
        float c = (lane == 0) ? vx : (lane == 1) ? vy : vz;
        out[point * 3 + lane] = c * vinv;
    }
}

extern "C" void kernel_launch(void* const* d_in, const int* in_sizes, int n_in,
                              void* d_out, int out_size, void* d_ws, size_t ws_size,
                              hipStream_t stream) {
    const float* pos = (const float*)d_in[0];
    const float* nbr = (const float*)d_in[1];
    const float* W1  = (const float*)d_in[2];
    const float* b1  = (const float*)d_in[3];
    const float* W2  = (const float*)d_in[4];
    const float* b2  = (const float*)d_in[5];
    const float* W3  = (const float*)d_in[6];
    const float* b3  = (const float*)d_in[7];
    float* out = (float*)d_out;

    const int N = in_sizes[0] / 3;            // 500000
    const int threads = 256;                  // 8 points per block
    const long long total = (long long)N * K; // one lane per (point, neighbor)
    const int blocks = (int)((total + threads - 1) / threads);

    velvec_kernel<<<blocks, threads, 0, stream>>>(pos, nbr, W1, b1, W2, b2, W3, b3,
                                                  out, N);
}